// Round 1
// baseline (328.738 us; speedup 1.0000x reference)
//
#include <hip/hip_runtime.h>

typedef __attribute__((ext_vector_type(8))) short short8;
typedef __attribute__((ext_vector_type(4))) short short4v;
typedef __attribute__((ext_vector_type(4))) float f32x4;

#define BATCH 65536
#define IN_DIM 784
#define HID 128
#define OUT_DIM 10
#define KPAD 800
#define NKS 25
#define BM 128
#define NBLK (BATCH / BM)

// workspace offsets (bytes), all 256-aligned
#define OFF_W1H 0
#define OFF_W1L 204800
#define OFF_W2S 409600
#define OFF_W3S 442368

__device__ __forceinline__ unsigned short bf16_rne(float f) {
    unsigned u = __float_as_uint(f);
    return (unsigned short)((u + 0x7FFFu + ((u >> 16) & 1u)) >> 16);
}
__device__ __forceinline__ float fast_tanh(float x) {
    float e = __expf(2.0f * x);
    return 1.0f - 2.0f / (e + 1.0f);
}

// Pre-pass: W1 -> k-padded (800), kstep-tiled [ks][col][32] bf16 hi/lo;
// W2 -> transposed [n][k] bf16; W3 -> transposed [j(pad16)][k] bf16.
__global__ void prep_kernel(const float* __restrict__ W1, const float* __restrict__ W2,
                            const float* __restrict__ W3,
                            unsigned short* __restrict__ w1h, unsigned short* __restrict__ w1l,
                            unsigned short* __restrict__ w2s, unsigned short* __restrict__ w3s) {
    int b = blockIdx.x, t = threadIdx.x;
    if (b < HID) {
        int col = b;
        for (int k = t; k < KPAD; k += 256) {
            float v = (k < IN_DIM) ? W1[k * HID + col] : 0.0f;
            unsigned u = __float_as_uint(v);
            unsigned short hi = (unsigned short)(u >> 16);       // trunc hi
            float hif = __uint_as_float(u & 0xFFFF0000u);
            unsigned short lo = bf16_rne(v - hif);               // rne lo
            int idx = ((k >> 5) * HID + col) * 32 + (k & 31);
            w1h[idx] = hi; w1l[idx] = lo;
        }
    } else if (b == HID) {
        for (int i = t; i < HID * HID; i += 256) {
            int n = i >> 7, k = i & 127;
            w2s[i] = bf16_rne(W2[k * HID + n]);
        }
    } else {
        for (int i = t; i < 16 * HID; i += 256) {
            int j = i >> 7, k = i & 127;
            float v = (j < OUT_DIM) ? W3[k * OUT_DIM + j] : 0.0f;
            w3s[i] = bf16_rne(v);
        }
    }
}

__launch_bounds__(256, 2)
__global__ void fused_kernel(const float* __restrict__ X,
                             const float* __restrict__ b1,
                             const float* __restrict__ b2,
                             const float* __restrict__ ob,
                             const float* __restrict__ csc,
                             const unsigned short* __restrict__ w1h,
                             const unsigned short* __restrict__ w1l,
                             const unsigned short* __restrict__ w2s,
                             const unsigned short* __restrict__ w3s,
                             float* __restrict__ OUT) {
    __shared__ float xs[BM][36];                 // x tile fp32, +pad (16B-aligned rows)
    __shared__ unsigned short w1hS[HID][40];     // [col][k] bf16 hi, pad->80B rows
    __shared__ unsigned short w1lS[HID][40];
    __shared__ unsigned short ht[HID][136];      // transposed h/z: [hcol][row] bf16

    const int t = threadIdx.x;
    const int wid = t >> 6, lane = t & 63;
    const int lg = lane >> 4, lr = lane & 15;
    const int row0 = blockIdx.x * BM;

    const float cs = csc[0];
    const float sgc = 1.0f / (1.0f + __expf(-cs));
    const float c = 0.001f * (0.5f + 1.5f * sgc);
    const float sc = sqrtf(c);

    // GEMM1 accumulators init with bias1 (C/D layout: col=lr+16f, row=4*lg+r)
    f32x4 acc[2][8];
    #pragma unroll
    for (int f = 0; f < 8; ++f) {
        float bv = b1[16 * f + lr];
        f32x4 v = {bv, bv, bv, bv};
        acc[0][f] = v; acc[1][f] = v;
    }

    const int srow = t >> 1;      // staging row / W1 col
    const int shalf = t & 1;      // 16-element half
    const float* xg = X + (size_t)(row0 + srow) * IN_DIM + shalf * 16;

    for (int ks = 0; ks < NKS; ++ks) {
        __syncthreads();
        {   // stage x tile (16 floats/thread, coalesced; zero-fill k>=784)
            int k0 = ks * 32;
            f32x4 v0 = {0,0,0,0}, v1 = v0, v2 = v0, v3 = v0;
            if (k0 + shalf * 16 < IN_DIM) {
                const f32x4* p = (const f32x4*)(xg + k0);
                v0 = p[0]; v1 = p[1]; v2 = p[2]; v3 = p[3];
            }
            f32x4* q = (f32x4*)(&xs[srow][shalf * 16]);
            q[0] = v0; q[1] = v1; q[2] = v2; q[3] = v3;
        }
        {   // stage W1 hi/lo tiles (pre-tiled contiguous in ws)
            const short8* gh = (const short8*)(w1h + (ks * HID + srow) * 32 + shalf * 16);
            const short8* gl = (const short8*)(w1l + (ks * HID + srow) * 32 + shalf * 16);
            short8 h0 = gh[0], h1 = gh[1], l0 = gl[0], l1 = gl[1];
            short8* qh = (short8*)(&w1hS[srow][shalf * 16]);
            short8* ql = (short8*)(&w1lS[srow][shalf * 16]);
            qh[0] = h0; qh[1] = h1; ql[0] = l0; ql[1] = l1;
        }
        __syncthreads();

        // A fragments: split x into bf16 hi/lo in-register (trunc split)
        short8 xh[2], xl[2];
        #pragma unroll
        for (int rf = 0; rf < 2; ++rf) {
            const int r = wid * 32 + rf * 16 + lr;
            const f32x4* p = (const f32x4*)(&xs[r][8 * lg]);
            f32x4 a = p[0], b = p[1];
            short8 h8, l8;
            #pragma unroll
            for (int j = 0; j < 8; ++j) {
                float v = (j < 4) ? a[j] : b[j - 4];
                unsigned u = __float_as_uint(v);
                h8[j] = (short)(u >> 16);
                float lof = v - __uint_as_float(u & 0xFFFF0000u);
                l8[j] = (short)(__float_as_uint(lof) >> 16);
            }
            xh[rf] = h8; xl[rf] = l8;
        }
        // 3-pass split MFMA (same k-map sigma for A and B -> self-consistent)
        #pragma unroll
        for (int f = 0; f < 8; ++f) {
            const short8 bh = *(const short8*)(&w1hS[16 * f + lr][8 * lg]);
            const short8 bl = *(const short8*)(&w1lS[16 * f + lr][8 * lg]);
            acc[0][f] = __builtin_amdgcn_mfma_f32_16x16x32_bf16(xh[0], bh, acc[0][f], 0, 0, 0);
            acc[1][f] = __builtin_amdgcn_mfma_f32_16x16x32_bf16(xh[1], bh, acc[1][f], 0, 0, 0);
            acc[0][f] = __builtin_amdgcn_mfma_f32_16x16x32_bf16(xl[0], bh, acc[0][f], 0, 0, 0);
            acc[1][f] = __builtin_amdgcn_mfma_f32_16x16x32_bf16(xl[1], bh, acc[1][f], 0, 0, 0);
            acc[0][f] = __builtin_amdgcn_mfma_f32_16x16x32_bf16(xh[0], bl, acc[0][f], 0, 0, 0);
            acc[1][f] = __builtin_amdgcn_mfma_f32_16x16x32_bf16(xh[1], bl, acc[1][f], 0, 0, 0);
        }
    }

    // h = tanh(.), keep fp32 in acc; write bf16 transpose to ht (wave-private rows)
    #pragma unroll
    for (int rf = 0; rf < 2; ++rf) {
        const int rbase = wid * 32 + rf * 16 + 4 * lg;
        #pragma unroll
        for (int f = 0; f < 8; ++f) {
            short4v pk;
            #pragma unroll
            for (int r = 0; r < 4; ++r) {
                float h = fast_tanh(acc[rf][f][r]);
                acc[rf][f][r] = h;
                pk[r] = (short)bf16_rne(h);
            }
            *(short4v*)(&ht[16 * f + lr][rbase]) = pk;
        }
    }

    // GEMM2: u = sigmoid(h @ W2 + b2), A from ht (scalar b16), B from global W2^T
    f32x4 uacc[2][8];
    #pragma unroll
    for (int f = 0; f < 8; ++f) {
        float bv = b2[16 * f + lr];
        f32x4 v = {bv, bv, bv, bv};
        uacc[0][f] = v; uacc[1][f] = v;
    }
    #pragma unroll
    for (int ks2 = 0; ks2 < 4; ++ks2) {
        short8 a2[2];
        #pragma unroll
        for (int rf = 0; rf < 2; ++rf) {
            const int rbl = wid * 32 + rf * 16 + lr;
            #pragma unroll
            for (int i = 0; i < 8; ++i)
                a2[rf][i] = (short)ht[ks2 * 32 + 8 * lg + i][rbl];
        }
        #pragma unroll
        for (int f = 0; f < 8; ++f) {
            const short8 bb = *(const short8*)(w2s + (16 * f + lr) * HID + ks2 * 32 + 8 * lg);
            uacc[0][f] = __builtin_amdgcn_mfma_f32_16x16x32_bf16(a2[0], bb, uacc[0][f], 0, 0, 0);
            uacc[1][f] = __builtin_amdgcn_mfma_f32_16x16x32_bf16(a2[1], bb, uacc[1][f], 0, 0, 0);
        }
    }
    #pragma unroll
    for (int rf = 0; rf < 2; ++rf)
        #pragma unroll
        for (int f = 0; f < 8; ++f)
            #pragma unroll
            for (int r = 0; r < 4; ++r)
                uacc[rf][f][r] = 1.0f / (1.0f + __expf(-uacc[rf][f][r]));

    // Mobius: per-row dots via 16-lane butterflies -> z = cA*h + cB*u
    float cA[2][4], cB[2][4];
    #pragma unroll
    for (int rf = 0; rf < 2; ++rf) {
        float hh[4] = {0,0,0,0}, uu[4] = {0,0,0,0}, hu[4] = {0,0,0,0};
        #pragma unroll
        for (int f = 0; f < 8; ++f)
            #pragma unroll
            for (int r = 0; r < 4; ++r) {
                float h = acc[rf][f][r], u = uacc[rf][f][r];
                hh[r] += h * h; uu[r] += u * u; hu[r] += h * u;
            }
        #pragma unroll
        for (int m = 1; m <= 8; m <<= 1)
            #pragma unroll
            for (int r = 0; r < 4; ++r) {
                hh[r] += __shfl_xor(hh[r], m);
                uu[r] += __shfl_xor(uu[r], m);
                hu[r] += __shfl_xor(hu[r], m);
            }
        #pragma unroll
        for (int r = 0; r < 4; ++r) {
            float nh = sqrtf(fmaxf(hh[r], 1e-14f));
            float nu = sqrtf(fmaxf(uu[r], 1e-14f));
            float argh = fminf(fmaxf(sc * nh, 1e-7f), 1.0f - 1e-5f);
            float argu = fminf(fmaxf(sc * nu, 1e-7f), 1.0f - 1e-5f);
            float ath = 0.5f * __logf((1.0f + argh) / (1.0f - argh));
            float atu = 0.5f * __logf((1.0f + argu) / (1.0f - argu));
            float alpha = fast_tanh(0.3f * ath) / (sc * nh);
            float beta  = fast_tanh(0.7f * atu) / (sc * nu);
            float UV = alpha * beta * hu[r];
            float UU = alpha * alpha * hh[r];
            float VV = beta * beta * uu[r];
            float den = fmaxf(1.0f + 2.0f * c * UV + c * c * UU * VV, 1e-7f);
            cA[rf][r] = (1.0f + 2.0f * c * UV + c * VV) * alpha / den;
            cB[rf][r] = (1.0f - c * UU) * beta / den;
        }
    }
    // write z (bf16) into ht, reusing wave-private rows
    #pragma unroll
    for (int rf = 0; rf < 2; ++rf) {
        const int rbase = wid * 32 + rf * 16 + 4 * lg;
        #pragma unroll
        for (int f = 0; f < 8; ++f) {
            short4v pk;
            #pragma unroll
            for (int r = 0; r < 4; ++r) {
                float z = cA[rf][r] * acc[rf][f][r] + cB[rf][r] * uacc[rf][f][r];
                pk[r] = (short)bf16_rne(z);
            }
            *(short4v*)(&ht[16 * f + lr][rbase]) = pk;
        }
    }

    // GEMM3: out = z @ W3 + ob via MFMA (cols padded to 16)
    float obv = (lr < OUT_DIM) ? ob[lr] : 0.0f;
    f32x4 oacc[2];
    oacc[0][0] = obv; oacc[0][1] = obv; oacc[0][2] = obv; oacc[0][3] = obv;
    oacc[1] = oacc[0];
    #pragma unroll
    for (int ks2 = 0; ks2 < 4; ++ks2) {
        short8 a3[2];
        #pragma unroll
        for (int rf = 0; rf < 2; ++rf) {
            const int rbl = wid * 32 + rf * 16 + lr;
            #pragma unroll
            for (int i = 0; i < 8; ++i)
                a3[rf][i] = (short)ht[ks2 * 32 + 8 * lg + i][rbl];
        }
        const short8 b3 = *(const short8*)(w3s + lr * HID + ks2 * 32 + 8 * lg);
        oacc[0] = __builtin_amdgcn_mfma_f32_16x16x32_bf16(a3[0], b3, oacc[0], 0, 0, 0);
        oacc[1] = __builtin_amdgcn_mfma_f32_16x16x32_bf16(a3[1], b3, oacc[1], 0, 0, 0);
    }
    if (lr < OUT_DIM) {
        #pragma unroll
        for (int rf = 0; rf < 2; ++rf) {
            const int rbase = row0 + wid * 32 + rf * 16 + 4 * lg;
            #pragma unroll
            for (int r = 0; r < 4; ++r)
                OUT[(size_t)(rbase + r) * OUT_DIM + lr] = oacc[rf][r];
        }
    }
}

extern "C" void kernel_launch(void* const* d_in, const int* in_sizes, int n_in,
                              void* d_out, int out_size, void* d_ws, size_t ws_size,
                              hipStream_t stream) {
    const float* X  = (const float*)d_in[0];
    const float* W1 = (const float*)d_in[1];
    const float* B1 = (const float*)d_in[2];
    const float* W2 = (const float*)d_in[3];
    const float* B2 = (const float*)d_in[4];
    const float* W3 = (const float*)d_in[5];
    const float* OB = (const float*)d_in[6];
    const float* CS = (const float*)d_in[7];
    unsigned short* w1h = (unsigned short*)((char*)d_ws + OFF_W1H);
    unsigned short* w1l = (unsigned short*)((char*)d_ws + OFF_W1L);
    unsigned short* w2s = (unsigned short*)((char*)d_ws + OFF_W2S);
    unsigned short* w3s = (unsigned short*)((char*)d_ws + OFF_W3S);
    prep_kernel<<<HID + 2, 256, 0, stream>>>(W1, W2, W3, w1h, w1l, w2s, w3s);
    fused_kernel<<<NBLK, 256, 0, stream>>>(X, B1, B2, OB, CS, w1h, w1l, w2s, w3s, (float*)d_out);
}

// Round 5
// 327.492 us; speedup vs baseline: 1.0038x; 1.0038x over previous
//
#include <hip/hip_runtime.h>

typedef __attribute__((ext_vector_type(8))) short short8;
typedef __attribute__((ext_vector_type(4))) short short4v;
typedef __attribute__((ext_vector_type(4))) float f32x4;

#define BATCH 65536
#define IN_DIM 784
#define HID 128
#define OUT_DIM 10
#define KPAD 800
#define NKS 25
#define BM 128
#define NBLK (BATCH / BM)

// workspace offsets (bytes), all 256-aligned
#define OFF_W1H 0
#define OFF_W1L 204800
#define OFF_W2S 409600
#define OFF_W3S 442368

__device__ __forceinline__ unsigned short bf16_rne(float f) {
    unsigned u = __float_as_uint(f);
    return (unsigned short)((u + 0x7FFFu + ((u >> 16) & 1u)) >> 16);
}
__device__ __forceinline__ float fast_tanh(float x) {
    float e = __expf(2.0f * x);
    return 1.0f - 2.0f / (e + 1.0f);
}

// Pre-pass: W1 -> k-padded (800), kstep-tiled [ks][col][32] bf16 hi/lo;
// W2 -> transposed [n][k] bf16; W3 -> transposed [j(pad16)][k] bf16.
__global__ void prep_kernel(const float* __restrict__ W1, const float* __restrict__ W2,
                            const float* __restrict__ W3,
                            unsigned short* __restrict__ w1h, unsigned short* __restrict__ w1l,
                            unsigned short* __restrict__ w2s, unsigned short* __restrict__ w3s) {
    int b = blockIdx.x, t = threadIdx.x;
    if (b < HID) {
        int col = b;
        for (int k = t; k < KPAD; k += 256) {
            float v = (k < IN_DIM) ? W1[k * HID + col] : 0.0f;
            unsigned u = __float_as_uint(v);
            unsigned short hi = (unsigned short)(u >> 16);       // trunc hi
            float hif = __uint_as_float(u & 0xFFFF0000u);
            unsigned short lo = bf16_rne(v - hif);               // rne lo
            int idx = ((k >> 5) * HID + col) * 32 + (k & 31);
            w1h[idx] = hi; w1l[idx] = lo;
        }
    } else if (b == HID) {
        for (int i = t; i < HID * HID; i += 256) {
            int n = i >> 7, k = i & 127;
            w2s[i] = bf16_rne(W2[k * HID + n]);
        }
    } else {
        for (int i = t; i < 16 * HID; i += 256) {
            int j = i >> 7, k = i & 127;
            float v = (j < OUT_DIM) ? W3[k * OUT_DIM + j] : 0.0f;
            w3s[i] = bf16_rne(v);
        }
    }
}

__launch_bounds__(256, 2)
__global__ void fused_kernel(const float* __restrict__ X,
                             const float* __restrict__ b1,
                             const float* __restrict__ b2,
                             const float* __restrict__ ob,
                             const float* __restrict__ csc,
                             const unsigned short* __restrict__ w1h,
                             const unsigned short* __restrict__ w1l,
                             const unsigned short* __restrict__ w2s,
                             const unsigned short* __restrict__ w3s,
                             float* __restrict__ OUT) {
    // [buf][hi/lo][col][kpad40] double-buffered W1 staging; ht aliased on top.
    __shared__ unsigned short smem[2][2][HID][40];         // 40960 B
    unsigned short (*ht)[136] = (unsigned short (*)[136])&smem[0][0][0][0]; // 34816 B

    const int t = threadIdx.x;
    const int wid = t >> 6, lane = t & 63;
    const int lg = lane >> 4, lr = lane & 15;
    const int row0 = blockIdx.x * BM;

    // GEMM1 accumulators init with bias1 (C/D layout: col=16f+lr, row=4*lg+r)
    f32x4 acc[2][8];
    #pragma unroll
    for (int f = 0; f < 8; ++f) {
        float bv = b1[16 * f + lr];
        f32x4 v = {bv, bv, bv, bv};
        acc[0][f] = v; acc[1][f] = v;
    }

    // ---- prefetch helpers (all static indexing) ----
    // x: each lane loads its own A-fragment bytes: rows wid*32+rf*16+lr, k = ks*32+8*lg..+8
    f32x4 xcur[2][2], xnxt[2][2];
    short8 wcur[4], wnxt[4];

    #define LOADX(dst, ks)                                                        \
        {                                                                         \
            int k0_ = (ks) * 32 + 8 * lg;                                         \
            _Pragma("unroll")                                                     \
            for (int rf = 0; rf < 2; ++rf) {                                      \
                f32x4 a_ = {0,0,0,0}, b_ = {0,0,0,0};                             \
                if (k0_ < IN_DIM) {                                               \
                    const f32x4* p_ = (const f32x4*)(X +                          \
                        (size_t)(row0 + wid * 32 + rf * 16 + lr) * IN_DIM + k0_); \
                    a_ = p_[0]; b_ = p_[1];                                       \
                }                                                                 \
                dst[rf][0] = a_; dst[rf][1] = b_;                                 \
            }                                                                     \
        }
    #define LOADW(dst, ks)                                                        \
        {                                                                         \
            const short8* ph_ = (const short8*)(w1h + (ks) * 4096) + t * 2;       \
            const short8* pl_ = (const short8*)(w1l + (ks) * 4096) + t * 2;       \
            dst[0] = ph_[0]; dst[1] = ph_[1];                                     \
            dst[2] = pl_[0]; dst[3] = pl_[1];                                     \
        }

    LOADX(xcur, 0);
    LOADW(wcur, 0);

    for (int ks = 0; ks < NKS; ++ks) {
        const int cur = ks & 1;
        {   // ds_write staged W1 regs (thread t -> col t>>1, k (t&1)*16..+16)
            short8* dh = (short8*)&smem[cur][0][t >> 1][(t & 1) * 16];
            short8* dl = (short8*)&smem[cur][1][t >> 1][(t & 1) * 16];
            dh[0] = wcur[0]; dh[1] = wcur[1];
            dl[0] = wcur[2]; dl[1] = wcur[3];
        }
        if (ks + 1 < NKS) {   // issue next-tile loads; they land during compute
            LOADX(xnxt, ks + 1);
            LOADW(wnxt, ks + 1);
        }
        __syncthreads();

        // split x into bf16 hi/lo in-register (trunc hi + rne lo)
        short8 xh[2], xl[2];
        #pragma unroll
        for (int rf = 0; rf < 2; ++rf) {
            short8 h8, l8;
            #pragma unroll
            for (int j = 0; j < 8; ++j) {
                float v = (j < 4) ? xcur[rf][0][j] : xcur[rf][1][j - 4];
                unsigned u = __float_as_uint(v);
                h8[j] = (short)(u >> 16);
                float lof = v - __uint_as_float(u & 0xFFFF0000u);
                l8[j] = (short)(__float_as_uint(lof) >> 16);
            }
            xh[rf] = h8; xl[rf] = l8;
        }
        // 3-pass split MFMA
        #pragma unroll
        for (int f = 0; f < 8; ++f) {
            const short8 bh = *(const short8*)&smem[cur][0][16 * f + lr][8 * lg];
            const short8 bl = *(const short8*)&smem[cur][1][16 * f + lr][8 * lg];
            acc[0][f] = __builtin_amdgcn_mfma_f32_16x16x32_bf16(xh[0], bh, acc[0][f], 0, 0, 0);
            acc[1][f] = __builtin_amdgcn_mfma_f32_16x16x32_bf16(xh[1], bh, acc[1][f], 0, 0, 0);
            acc[0][f] = __builtin_amdgcn_mfma_f32_16x16x32_bf16(xl[0], bh, acc[0][f], 0, 0, 0);
            acc[1][f] = __builtin_amdgcn_mfma_f32_16x16x32_bf16(xl[1], bh, acc[1][f], 0, 0, 0);
            acc[0][f] = __builtin_amdgcn_mfma_f32_16x16x32_bf16(xh[0], bl, acc[0][f], 0, 0, 0);
            acc[1][f] = __builtin_amdgcn_mfma_f32_16x16x32_bf16(xh[1], bl, acc[1][f], 0, 0, 0);
        }
        // rotate double-buffered registers
        #pragma unroll
        for (int rf = 0; rf < 2; ++rf) { xcur[rf][0] = xnxt[rf][0]; xcur[rf][1] = xnxt[rf][1]; }
        #pragma unroll
        for (int j = 0; j < 4; ++j) wcur[j] = wnxt[j];
    }
    __syncthreads();   // all waves done with W1 buffers before ht alias is written

    const float cs = csc[0];
    const float sgc = 1.0f / (1.0f + __expf(-cs));
    const float c = 0.001f * (0.5f + 1.5f * sgc);
    const float sc = sqrtf(c);

    // h = tanh(.), keep fp32 in acc; write bf16 transpose to ht (wave-private rows)
    #pragma unroll
    for (int rf = 0; rf < 2; ++rf) {
        const int rbase = wid * 32 + rf * 16 + 4 * lg;
        #pragma unroll
        for (int f = 0; f < 8; ++f) {
            short4v pk;
            #pragma unroll
            for (int r = 0; r < 4; ++r) {
                float h = fast_tanh(acc[rf][f][r]);
                acc[rf][f][r] = h;
                pk[r] = (short)bf16_rne(h);
            }
            *(short4v*)(&ht[16 * f + lr][rbase]) = pk;
        }
    }

    // GEMM2: u = sigmoid(h @ W2 + b2), A from ht, B from global W2^T (L2-resident)
    f32x4 uacc[2][8];
    #pragma unroll
    for (int f = 0; f < 8; ++f) {
        float bv = b2[16 * f + lr];
        f32x4 v = {bv, bv, bv, bv};
        uacc[0][f] = v; uacc[1][f] = v;
    }
    #pragma unroll
    for (int ks2 = 0; ks2 < 4; ++ks2) {
        short8 a2[2];
        #pragma unroll
        for (int rf = 0; rf < 2; ++rf) {
            const int rbl = wid * 32 + rf * 16 + lr;
            #pragma unroll
            for (int i = 0; i < 8; ++i)
                a2[rf][i] = (short)ht[ks2 * 32 + 8 * lg + i][rbl];
        }
        #pragma unroll
        for (int f = 0; f < 8; ++f) {
            const short8 bb = *(const short8*)(w2s + (16 * f + lr) * HID + ks2 * 32 + 8 * lg);
            uacc[0][f] = __builtin_amdgcn_mfma_f32_16x16x32_bf16(a2[0], bb, uacc[0][f], 0, 0, 0);
            uacc[1][f] = __builtin_amdgcn_mfma_f32_16x16x32_bf16(a2[1], bb, uacc[1][f], 0, 0, 0);
        }
    }
    #pragma unroll
    for (int rf = 0; rf < 2; ++rf)
        #pragma unroll
        for (int f = 0; f < 8; ++f)
            #pragma unroll
            for (int r = 0; r < 4; ++r)
                uacc[rf][f][r] = 1.0f / (1.0f + __expf(-uacc[rf][f][r]));

    // Mobius: per-row dots via 16-lane butterflies -> z = cA*h + cB*u
    float cA[2][4], cB[2][4];
    #pragma unroll
    for (int rf = 0; rf < 2; ++rf) {
        float hh[4] = {0,0,0,0}, uu[4] = {0,0,0,0}, hu[4] = {0,0,0,0};
        #pragma unroll
        for (int f = 0; f < 8; ++f)
            #pragma unroll
            for (int r = 0; r < 4; ++r) {
                float h = acc[rf][f][r], u = uacc[rf][f][r];
                hh[r] += h * h; uu[r] += u * u; hu[r] += h * u;
            }
        #pragma unroll
        for (int m = 1; m <= 8; m <<= 1)
            #pragma unroll
            for (int r = 0; r < 4; ++r) {
                hh[r] += __shfl_xor(hh[r], m);
                uu[r] += __shfl_xor(uu[r], m);
                hu[r] += __shfl_xor(hu[r], m);
            }
        #pragma unroll
        for (int r = 0; r < 4; ++r) {
            float nh = sqrtf(fmaxf(hh[r], 1e-14f));
            float nu = sqrtf(fmaxf(uu[r], 1e-14f));
            float argh = fminf(fmaxf(sc * nh, 1e-7f), 1.0f - 1e-5f);
            float argu = fminf(fmaxf(sc * nu, 1e-7f), 1.0f - 1e-5f);
            float ath = 0.5f * __logf((1.0f + argh) / (1.0f - argh));
            float atu = 0.5f * __logf((1.0f + argu) / (1.0f - argu));
            float alpha = fast_tanh(0.3f * ath) / (sc * nh);
            float beta  = fast_tanh(0.7f * atu) / (sc * nu);
            float UV = alpha * beta * hu[r];
            float UU = alpha * alpha * hh[r];
            float VV = beta * beta * uu[r];
            float den = fmaxf(1.0f + 2.0f * c * UV + c * c * UU * VV, 1e-7f);
            cA[rf][r] = (1.0f + 2.0f * c * UV + c * VV) * alpha / den;
            cB[rf][r] = (1.0f - c * UU) * beta / den;
        }
    }
    // write z (bf16) into ht, reusing wave-private rows
    #pragma unroll
    for (int rf = 0; rf < 2; ++rf) {
        const int rbase = wid * 32 + rf * 16 + 4 * lg;
        #pragma unroll
        for (int f = 0; f < 8; ++f) {
            short4v pk;
            #pragma unroll
            for (int r = 0; r < 4; ++r) {
                float z = cA[rf][r] * acc[rf][f][r] + cB[rf][r] * uacc[rf][f][r];
                pk[r] = (short)bf16_rne(z);
            }
            *(short4v*)(&ht[16 * f + lr][rbase]) = pk;
        }
    }

    // GEMM3: out = z @ W3 + ob via MFMA (cols padded to 16)
    float obv = (lr < OUT_DIM) ? ob[lr] : 0.0f;
    f32x4 oacc[2];
    oacc[0][0] = obv; oacc[0][1] = obv; oacc[0][2] = obv; oacc[0][3] = obv;
    oacc[1] = oacc[0];
    #pragma unroll
    for (int ks2 = 0; ks2 < 4; ++ks2) {
        short8 a3[2];
        #pragma unroll
        for (int rf = 0; rf < 2; ++rf) {
            const int rbl = wid * 32 + rf * 16 + lr;
            #pragma unroll
            for (int i = 0; i < 8; ++i)
                a3[rf][i] = (short)ht[ks2 * 32 + 8 * lg + i][rbl];
        }
        const short8 b3 = *(const short8*)(w3s + lr * HID + ks2 * 32 + 8 * lg);
        oacc[0] = __builtin_amdgcn_mfma_f32_16x16x32_bf16(a3[0], b3, oacc[0], 0, 0, 0);
        oacc[1] = __builtin_amdgcn_mfma_f32_16x16x32_bf16(a3[1], b3, oacc[1], 0, 0, 0);
    }
    if (lr < OUT_DIM) {
        #pragma unroll
        for (int rf = 0; rf < 2; ++rf) {
            const int rbase = row0 + wid * 32 + rf * 16 + 4 * lg;
            #pragma unroll
            for (int r = 0; r < 4; ++r)
                OUT[(size_t)(rbase + r) * OUT_DIM + lr] = oacc[rf][r];
        }
    }
}

extern "C" void kernel_launch(void* const* d_in, const int* in_sizes, int n_in,
                              void* d_out, int out_size, void* d_ws, size_t ws_size,
                              hipStream_t stream) {
    const float* X  = (const float*)d_in[0];
    const float* W1 = (const float*)d_in[1];
    const float* B1 = (const float*)d_in[2];
    const float* W2 = (const float*)d_in[3];
    const float* B2 = (const float*)d_in[4];
    const float* W3 = (const float*)d_in[5];
    const float* OB = (const float*)d_in[6];
    const float* CS = (const float*)d_in[7];
    unsigned short* w1h = (unsigned short*)((char*)d_ws + OFF_W1H);
    unsigned short* w1l = (unsigned short*)((char*)d_ws + OFF_W1L);
    unsigned short* w2s = (unsigned short*)((char*)d_ws + OFF_W2S);
    unsigned short* w3s = (unsigned short*)((char*)d_ws + OFF_W3S);
    prep_kernel<<<HID + 2, 256, 0, stream>>>(W1, W2, W3, w1h, w1l, w2s, w3s);
    fused_kernel<<<NBLK, 256, 0, stream>>>(X, B1, B2, OB, CS, w1h, w1l, w2s, w3s, (float*)d_out);
}